// Round 14
// baseline (582.300 us; speedup 1.0000x reference)
//
#include <hip/hip_runtime.h>

// ---------------------------------------------------------------------------
// HedgeHog attention distillation map: pred = (fq.fk^T) rownorm, true = softmax(q0.k0^T/8)
// Output [2,2,16,2048,2048] fp32 = 1.07 GiB -> HBM-write-bound.
//
// v14 = v13 (LDS-resident slab operands, the first structure to beat the
// 2.2 TB/s wall) + :
//  - k_write: 8 waves/block (16 waves/CU), 2-deep store-reg rotation across
//    the unrolled rg loop, per-block rg-order stagger (write-phase decorrel).
//  - normalizers split: k_normT (grid 32x64, clean-L2 phase, 4x parallel) +
//    k_normP (tiny pred dot). No serial prologue inside the write storm.
// ---------------------------------------------------------------------------

typedef __attribute__((ext_vector_type(8))) short  bf16x8;
typedef __attribute__((ext_vector_type(4))) float  f32x4;

#define NN 2048
#define NBH 32

__device__ float g_part[NBH * 8 * 128];   // fk colsum partials
__device__ float g_normP[NBH * NN];       // 1 / pred row sum
__device__ float g_normT[NBH * NN];       // 1 / true row sum

__device__ __forceinline__ float bf2f(unsigned short u) {
  union { unsigned int i; float f; } v; v.i = ((unsigned int)u) << 16; return v.f;
}
__device__ __forceinline__ unsigned short f2bf(float f) {
  union { float f; unsigned int i; } v; v.f = f;
  unsigned int x = v.i;
  return (unsigned short)((x + 0x7FFFu + ((x >> 16) & 1u)) >> 16);  // RNE
}
__device__ __forceinline__ bf16x8 cvt8(const float* __restrict__ p) {
  bf16x8 v;
#pragma unroll
  for (int i = 0; i < 8; i++) v[i] = (short)f2bf(p[i]);
  return v;
}
__device__ __forceinline__ f32x4 mfma16(bf16x8 a, bf16x8 b, f32x4 c) {
  return __builtin_amdgcn_mfma_f32_16x16x32_bf16(a, b, c, 0, 0, 0);
}

// ---------------------------------------------------------------------------
// Kernel 1: projections + hedgehog features. One wave owns 16 rows.
// ---------------------------------------------------------------------------
__device__ __forceinline__ void proj_chain(
    const bf16x8 ax[2],
    const float* __restrict__ W1, const float* __restrict__ b1,
    const float* __restrict__ W2, const float* __restrict__ b2,
    unsigned short* __restrict__ o1w, unsigned short* __restrict__ o2w,
    unsigned short (*Tq)[72], unsigned short (*Tf)[136],
    long r0, int l15, int g, int l)
{
#pragma unroll
  for (int nt = 0; nt < 4; nt++) {
    f32x4 acc = {0.f, 0.f, 0.f, 0.f};
    acc = mfma16(ax[0], cvt8(W1 + (nt * 16 + l15) * 64 + g * 8), acc);
    acc = mfma16(ax[1], cvt8(W1 + (nt * 16 + l15) * 64 + 32 + g * 8), acc);
    float bv = b1[nt * 16 + l15];
#pragma unroll
    for (int j = 0; j < 4; j++)
      Tq[g * 4 + j][nt * 16 + l15] = f2bf(acc[j] + bv);   // C layout: row=(l>>4)*4+j, col=l&15
  }
#pragma unroll
  for (int i = 0; i < 2; i++) {
    int c = i * 64 + l;
    int r = c >> 3, cc = c & 7;
    *(bf16x8*)(o1w + (r0 + r) * 64 + cc * 8) = *(const bf16x8*)&Tq[r][cc * 8];
  }
  bf16x8 a1[2];
#pragma unroll
  for (int kk = 0; kk < 2; kk++)
    a1[kk] = *(const bf16x8*)&Tq[l15][kk * 32 + g * 8];
#pragma unroll
  for (int nt = 0; nt < 4; nt++) {
    f32x4 acc = {0.f, 0.f, 0.f, 0.f};
    acc = mfma16(a1[0], cvt8(W2 + (nt * 16 + l15) * 64 + g * 8), acc);
    acc = mfma16(a1[1], cvt8(W2 + (nt * 16 + l15) * 64 + 32 + g * 8), acc);
    float bv = b2[nt * 16 + l15];
#pragma unroll
    for (int j = 0; j < 4; j++) {
      float h = acc[j] + bv;
      Tf[g * 4 + j][nt * 16 + l15]      = f2bf(__expf(h));
      Tf[g * 4 + j][64 + nt * 16 + l15] = f2bf(__expf(-h));
    }
  }
#pragma unroll
  for (int i = 0; i < 4; i++) {
    int c = i * 64 + l;
    int r = c >> 4, cc = c & 15;
    *(bf16x8*)(o2w + (r0 + r) * 128 + cc * 8) = *(const bf16x8*)&Tf[r][cc * 8];
  }
}

__global__ __launch_bounds__(256) void k_proj(
    const float* __restrict__ x,
    const float* __restrict__ Wq,  const float* __restrict__ bq,
    const float* __restrict__ Wk,  const float* __restrict__ bk,
    const float* __restrict__ Wmq, const float* __restrict__ bmq,
    const float* __restrict__ Wmk, const float* __restrict__ bmk,
    unsigned short* __restrict__ q0w, unsigned short* __restrict__ k0w,
    unsigned short* __restrict__ fqw, unsigned short* __restrict__ fkw)
{
  const int tid = threadIdx.x;
  const int w = tid >> 6, l = tid & 63;
  const int l15 = l & 15, g = l >> 4;
  const long r0 = ((long)blockIdx.x * 4 + w) * 16;

  __shared__ unsigned short TqS[4][16][72];
  __shared__ unsigned short TfS[4][16][136];

  bf16x8 ax[2];
#pragma unroll
  for (int kk = 0; kk < 2; kk++)
    ax[kk] = cvt8(x + (r0 + l15) * 64 + kk * 32 + g * 8);

  proj_chain(ax, Wq, bq, Wmq, bmq, q0w, fqw, TqS[w], TfS[w], r0, l15, g, l);
  proj_chain(ax, Wk, bk, Wmk, bmk, k0w, fkw, TqS[w], TfS[w], r0, l15, g, l);
}

// ---------------------------------------------------------------------------
// Kernel 2: fk column-sum partials (bh, part): rows part*256..+255.
// ---------------------------------------------------------------------------
__global__ __launch_bounds__(256) void k_colsum1(const unsigned short* __restrict__ fkw)
{
  const int bh = blockIdx.x, part = blockIdx.y;
  const int tid = threadIdx.x;
  const int cg = tid & 15, rg = tid >> 4;
  const unsigned short* fkp = fkw + ((long)bh * NN + part * 256 + rg * 16) * 128 + cg * 8;

  float a8[8] = {0.f, 0.f, 0.f, 0.f, 0.f, 0.f, 0.f, 0.f};
#pragma unroll
  for (int r = 0; r < 16; r++) {
    bf16x8 v = *(const bf16x8*)(fkp + (long)r * 128);
#pragma unroll
    for (int j = 0; j < 8; j++) a8[j] += bf2f((unsigned short)v[j]);
  }
  __shared__ float red[16][132];
#pragma unroll
  for (int j = 0; j < 8; j++) red[rg][cg * 8 + j] = a8[j];
  __syncthreads();
  if (tid < 128) {
    float s = 0.f;
#pragma unroll
    for (int r = 0; r < 16; r++) s += red[r][tid];
    g_part[(bh * 8 + part) * 128 + tid] = s;
  }
}

// ---------------------------------------------------------------------------
// Kernel 3a: pred normalizers (factorized dot with fk colsums).
// ---------------------------------------------------------------------------
__global__ __launch_bounds__(256) void k_normP(const unsigned short* __restrict__ fqw)
{
  const int bh = blockIdx.x, rg = blockIdx.y;   // (32, 16)
  const int tid = threadIdx.x;

  __shared__ float sfk[128];
  if (tid < 128) {
    float s = 0.f;
#pragma unroll
    for (int pt = 0; pt < 8; pt++) s += g_part[bh * 1024 + pt * 128 + tid];
    sfk[tid] = s;
  }
  __syncthreads();
  if (tid < 128) {
    const int row = rg * 128 + tid;
    const unsigned short* p = fqw + ((long)bh * NN + row) * 128;
    float d = 0.f;
#pragma unroll
    for (int i = 0; i < 16; i++) {
      bf16x8 v = *(const bf16x8*)(p + i * 8);
#pragma unroll
      for (int jj = 0; jj < 8; jj++) d += bf2f((unsigned short)v[jj]) * sfk[i * 8 + jj];
    }
    g_normP[bh * NN + row] = 1.0f / d;
  }
}

// ---------------------------------------------------------------------------
// Kernel 3b: true normalizers. Grid (32, 64): 32 rows/block, keys split
// across 4 waves. Runs before the write storm (clean L2).
// ---------------------------------------------------------------------------
__global__ __launch_bounds__(256) void k_normT(
    const unsigned short* __restrict__ q0w, const unsigned short* __restrict__ k0w)
{
  const int bh = blockIdx.x, rb = blockIdx.y * 32;
  const int tid = threadIdx.x;
  const int w = tid >> 6, l = tid & 63;
  const int l15 = l & 15, g = l >> 4;

  __shared__ float sred[2][4][16];
  const unsigned short* k0p = k0w + (long)bh * NN * 64;

#pragma unroll
  for (int tt = 0; tt < 2; tt++) {
    const unsigned short* qp = q0w + ((long)bh * NN + rb + tt * 16) * 64;
    bf16x8 a0 = *(const bf16x8*)(qp + l15 * 64 + g * 8);
    bf16x8 a1 = *(const bf16x8*)(qp + l15 * 64 + 32 + g * 8);
    float st[4] = {0.f, 0.f, 0.f, 0.f};
    for (int kt = w; kt < 128; kt += 4) {
      const unsigned short* bp = k0p + (long)(kt * 16 + l15) * 64 + g * 8;
      f32x4 acc = {0.f, 0.f, 0.f, 0.f};
      acc = mfma16(a0, *(const bf16x8*)bp, acc);
      acc = mfma16(a1, *(const bf16x8*)(bp + 32), acc);
#pragma unroll
      for (int j = 0; j < 4; j++) st[j] += __expf(acc[j] * 0.125f);
    }
#pragma unroll
    for (int j = 0; j < 4; j++) {
      float v = st[j];
      v += __shfl_xor(v, 1, 16);
      v += __shfl_xor(v, 2, 16);
      v += __shfl_xor(v, 4, 16);
      v += __shfl_xor(v, 8, 16);
      if (l15 == 0) sred[tt][w][g * 4 + j] = v;
    }
  }
  __syncthreads();
  if (tid < 32) {
    const int t2 = tid >> 4, rr = tid & 15;
    float s = sred[t2][0][rr] + sred[t2][1][rr] + sred[t2][2][rr] + sred[t2][3][rr];
    g_normT[bh * NN + rb + t2 * 16 + rr] = 1.0f / s;
  }
}

// ---------------------------------------------------------------------------
// Kernel 4: slab writer. Block = (bh, 128-key slab), 8 waves, 2 blocks/CU.
// fk/k0 slab LDS-resident; sweep 128 row-groups (order staggered per block).
// Store-data regs rotated 2-deep across the unrolled rg loop.
// ---------------------------------------------------------------------------
__global__ __launch_bounds__(512, 4) void k_write(
    const unsigned short* __restrict__ q0w, const unsigned short* __restrict__ k0w,
    const unsigned short* __restrict__ fqw, const unsigned short* __restrict__ fkw,
    float* __restrict__ out)
{
  const int bh = blockIdx.x;          // 0..31
  const int slab = blockIdx.y;        // 0..15
  const int tid = threadIdx.x;
  const int w = tid >> 6, l = tid & 63;
  const int l15 = l & 15, g = l >> 4;
  const int off = (bh * 37 + slab * 53) & 127;   // rg-order stagger

  __shared__ unsigned short fkS[128][136];  // slab operands (padded rows)
  __shared__ unsigned short k0S[128][72];
  __shared__ float obuf[2][16][132];        // [0]=pred strip, [1]=true strip

  const unsigned short* fkp = fkw + ((long)bh * NN + slab * 128) * 128;
  const unsigned short* k0p = k0w + ((long)bh * NN + slab * 128) * 64;
  const unsigned short* fqb = fqw + (long)bh * NN * 128;
  const unsigned short* q0b = q0w + (long)bh * NN * 64;
  const float* npb = g_normP + bh * NN;
  const float* ntb = g_normT + bh * NN;
  const long ob_p0 = (long)bh * NN * NN + slab * 128;
  const long ob_t0 = ob_p0 + (long)NBH * NN * NN;

  // ---- stage slab operands once (512 threads) ----
#pragma unroll
  for (int i = 0; i < 4; i++) {
    int c = i * 512 + tid, r = c >> 4, cc = c & 15;
    *(bf16x8*)&fkS[r][cc * 8] = *(const bf16x8*)(fkp + (long)r * 128 + cc * 8);
  }
#pragma unroll
  for (int i = 0; i < 2; i++) {
    int c = i * 512 + tid, r = c >> 3, cc = c & 7;
    *(bf16x8*)&k0S[r][cc * 8] = *(const bf16x8*)(k0p + (long)r * 64 + cc * 8);
  }
  __syncthreads();

  bf16x8 aq[4], bq_[4], ak[2], bk_[2];
  f32x4 aip, ait, bip, bit;
  f32x4 p0, p1, t0, t1;               // store-data regs, rotated 2-deep

#define PF(RG1, FQ, K0, IP, IT) {                                              \
    if ((RG1) < 128) {                                                         \
      const int qr_ = (((RG1) + off) & 127) * 16;                              \
      _Pragma("unroll")                                                        \
      for (int kk = 0; kk < 4; kk++)                                           \
        FQ[kk] = *(const bf16x8*)(fqb + (long)(qr_ + l15) * 128 + kk * 32 + g * 8); \
      _Pragma("unroll")                                                        \
      for (int kk = 0; kk < 2; kk++)                                           \
        K0[kk] = *(const bf16x8*)(q0b + (long)(qr_ + l15) * 64 + kk * 32 + g * 8);  \
      IP = *(const f32x4*)(npb + qr_ + g * 4);                                 \
      IT = *(const f32x4*)(ntb + qr_ + g * 4);                                 \
    }                                                                          \
  }

#define CPRED(FQ, IP) {                                                        \
    const int key = w * 16 + l15;                                              \
    f32x4 acc = {0.f, 0.f, 0.f, 0.f};                                          \
    _Pragma("unroll")                                                          \
    for (int kk = 0; kk < 4; kk++)                                             \
      acc = mfma16(FQ[kk], *(const bf16x8*)&fkS[key][kk * 32 + g * 8], acc);   \
    _Pragma("unroll")                                                          \
    for (int j = 0; j < 4; j++)                                                \
      obuf[0][g * 4 + j][key] = acc[j] * IP[j];                                \
  }

#define CTRUE(K0, IT) {                                                        \
    const int key = w * 16 + l15;                                              \
    f32x4 acc = {0.f, 0.f, 0.f, 0.f};                                          \
    acc = mfma16(K0[0], *(const bf16x8*)&k0S[key][g * 8], acc);                \
    acc = mfma16(K0[1], *(const bf16x8*)&k0S[key][32 + g * 8], acc);           \
    _Pragma("unroll")                                                          \
    for (int j = 0; j < 4; j++)                                                \
      obuf[1][g * 4 + j][key] = __expf(acc[j] * 0.125f) * IT[j];               \
  }

#define STOREV(PL, RG2, V) {                                                   \
    const int rge_ = ((RG2) + off) & 127;                                      \
    const long ob = ((PL) ? ob_t0 : ob_p0) + (long)(rge_ * 16) * NN;           \
    const int row = w * 2 + (l >> 5), col = (l & 31) * 4;                      \
    V = *(const f32x4*)&obuf[PL][row][col];                                    \
    *(f32x4*)(out + ob + (long)row * NN + col) = V;                            \
  }

#define BODY(RG, FQ, K0, IP, IT, NFQ, NK0, NIP, NIT, P, T) {                   \
    /* --- pred segment --- */                                                 \
    PF((RG) + 1, NFQ, NK0, NIP, NIT);                                          \
    if ((RG) > 0) STOREV(1, (RG) - 1, T);                                      \
    CPRED(FQ, IP);                                                             \
    asm volatile("s_waitcnt lgkmcnt(0)" ::: "memory");                         \
    __builtin_amdgcn_s_barrier();                                              \
    __builtin_amdgcn_sched_barrier(0);                                         \
    /* --- true segment --- */                                                 \
    STOREV(0, RG, P);                                                          \
    CTRUE(K0, IT);                                                             \
    asm volatile("s_waitcnt lgkmcnt(0)" ::: "memory");                         \
    __builtin_amdgcn_s_barrier();                                              \
    __builtin_amdgcn_sched_barrier(0);                                         \
  }

  PF(0, aq, ak, aip, ait);            // row-group 0 operands

#pragma unroll 1
  for (int rg2 = 0; rg2 < 64; rg2++) {
    BODY(2 * rg2,     aq, ak, aip, ait, bq_, bk_, bip, bit, p0, t0);
    BODY(2 * rg2 + 1, bq_, bk_, bip, bit, aq, ak, aip, ait, p1, t1);
  }
  STOREV(1, 127, t0);                 // drain: last true strip

#undef PF
#undef CPRED
#undef CTRUE
#undef STOREV
#undef BODY
}

extern "C" void kernel_launch(void* const* d_in, const int* in_sizes, int n_in,
                              void* d_out, int out_size, void* d_ws, size_t ws_size,
                              hipStream_t stream) {
  const float* x   = (const float*)d_in[0];
  const float* Wq  = (const float*)d_in[1];
  const float* bq  = (const float*)d_in[2];
  const float* Wk  = (const float*)d_in[3];
  const float* bk  = (const float*)d_in[4];
  const float* Wmq = (const float*)d_in[5];
  const float* bmq = (const float*)d_in[6];
  const float* Wmk = (const float*)d_in[7];
  const float* bmk = (const float*)d_in[8];
  float* out = (float*)d_out;

  // ws layout (bf16): q0[32][2048][64], k0[...], fq[32][2048][128], fk[...] = 48 MB
  unsigned short* q0w = (unsigned short*)d_ws;
  unsigned short* k0w = q0w + (long)NBH * NN * 64;
  unsigned short* fqw = k0w + (long)NBH * NN * 64;
  unsigned short* fkw = fqw + (long)NBH * NN * 128;

  hipLaunchKernelGGL(k_proj, dim3(1024), dim3(256), 0, stream,
                     x, Wq, bq, Wk, bk, Wmq, bmq, Wmk, bmk, q0w, k0w, fqw, fkw);
  hipLaunchKernelGGL(k_colsum1, dim3(NBH, 8), dim3(256), 0, stream, fkw);
  hipLaunchKernelGGL(k_normP, dim3(NBH, 16), dim3(256), 0, stream, fqw);
  hipLaunchKernelGGL(k_normT, dim3(NBH, 64), dim3(256), 0, stream, q0w, k0w);
  hipLaunchKernelGGL(k_write, dim3(NBH, 16), dim3(512), 0, stream,
                     q0w, k0w, fqw, fkw, out);
}

// Round 15
// 491.341 us; speedup vs baseline: 1.1851x; 1.1851x over previous
//
#include <hip/hip_runtime.h>

// ---------------------------------------------------------------------------
// HedgeHog attention distillation map: pred = (fq.fk^T) rownorm, true = softmax(q0.k0^T/8)
// Output [2,2,16,2048,2048] fp32 = 1.07 GiB -> HBM-write-bound.
//
// v15 = v13 (best: 487us) de-confounded from v14's regression:
//  - KEEP: 4-wave blocks, UNIFORM sweep order (cross-block A-stream L2 hits
//    under write thrash -- v14's stagger broke this: 582us).
//  - ADD: parallel normalizers (k_normP/k_normT, no serial straggler).
//  - ADD: 2-deep store-register rotation (WAR reuse distance 2 segments).
// ---------------------------------------------------------------------------

typedef __attribute__((ext_vector_type(8))) short  bf16x8;
typedef __attribute__((ext_vector_type(4))) float  f32x4;

#define NN 2048
#define NBH 32

__device__ float g_part[NBH * 8 * 128];   // fk colsum partials
__device__ float g_normP[NBH * NN];       // 1 / pred row sum
__device__ float g_normT[NBH * NN];       // 1 / true row sum

__device__ __forceinline__ float bf2f(unsigned short u) {
  union { unsigned int i; float f; } v; v.i = ((unsigned int)u) << 16; return v.f;
}
__device__ __forceinline__ unsigned short f2bf(float f) {
  union { float f; unsigned int i; } v; v.f = f;
  unsigned int x = v.i;
  return (unsigned short)((x + 0x7FFFu + ((x >> 16) & 1u)) >> 16);  // RNE
}
__device__ __forceinline__ bf16x8 cvt8(const float* __restrict__ p) {
  bf16x8 v;
#pragma unroll
  for (int i = 0; i < 8; i++) v[i] = (short)f2bf(p[i]);
  return v;
}
__device__ __forceinline__ f32x4 mfma16(bf16x8 a, bf16x8 b, f32x4 c) {
  return __builtin_amdgcn_mfma_f32_16x16x32_bf16(a, b, c, 0, 0, 0);
}

// ---------------------------------------------------------------------------
// Kernel 1: projections + hedgehog features. One wave owns 16 rows.
// ---------------------------------------------------------------------------
__device__ __forceinline__ void proj_chain(
    const bf16x8 ax[2],
    const float* __restrict__ W1, const float* __restrict__ b1,
    const float* __restrict__ W2, const float* __restrict__ b2,
    unsigned short* __restrict__ o1w, unsigned short* __restrict__ o2w,
    unsigned short (*Tq)[72], unsigned short (*Tf)[136],
    long r0, int l15, int g, int l)
{
#pragma unroll
  for (int nt = 0; nt < 4; nt++) {
    f32x4 acc = {0.f, 0.f, 0.f, 0.f};
    acc = mfma16(ax[0], cvt8(W1 + (nt * 16 + l15) * 64 + g * 8), acc);
    acc = mfma16(ax[1], cvt8(W1 + (nt * 16 + l15) * 64 + 32 + g * 8), acc);
    float bv = b1[nt * 16 + l15];
#pragma unroll
    for (int j = 0; j < 4; j++)
      Tq[g * 4 + j][nt * 16 + l15] = f2bf(acc[j] + bv);   // C layout: row=(l>>4)*4+j, col=l&15
  }
#pragma unroll
  for (int i = 0; i < 2; i++) {
    int c = i * 64 + l;
    int r = c >> 3, cc = c & 7;
    *(bf16x8*)(o1w + (r0 + r) * 64 + cc * 8) = *(const bf16x8*)&Tq[r][cc * 8];
  }
  bf16x8 a1[2];
#pragma unroll
  for (int kk = 0; kk < 2; kk++)
    a1[kk] = *(const bf16x8*)&Tq[l15][kk * 32 + g * 8];
#pragma unroll
  for (int nt = 0; nt < 4; nt++) {
    f32x4 acc = {0.f, 0.f, 0.f, 0.f};
    acc = mfma16(a1[0], cvt8(W2 + (nt * 16 + l15) * 64 + g * 8), acc);
    acc = mfma16(a1[1], cvt8(W2 + (nt * 16 + l15) * 64 + 32 + g * 8), acc);
    float bv = b2[nt * 16 + l15];
#pragma unroll
    for (int j = 0; j < 4; j++) {
      float h = acc[j] + bv;
      Tf[g * 4 + j][nt * 16 + l15]      = f2bf(__expf(h));
      Tf[g * 4 + j][64 + nt * 16 + l15] = f2bf(__expf(-h));
    }
  }
#pragma unroll
  for (int i = 0; i < 4; i++) {
    int c = i * 64 + l;
    int r = c >> 4, cc = c & 15;
    *(bf16x8*)(o2w + (r0 + r) * 128 + cc * 8) = *(const bf16x8*)&Tf[r][cc * 8];
  }
}

__global__ __launch_bounds__(256) void k_proj(
    const float* __restrict__ x,
    const float* __restrict__ Wq,  const float* __restrict__ bq,
    const float* __restrict__ Wk,  const float* __restrict__ bk,
    const float* __restrict__ Wmq, const float* __restrict__ bmq,
    const float* __restrict__ Wmk, const float* __restrict__ bmk,
    unsigned short* __restrict__ q0w, unsigned short* __restrict__ k0w,
    unsigned short* __restrict__ fqw, unsigned short* __restrict__ fkw)
{
  const int tid = threadIdx.x;
  const int w = tid >> 6, l = tid & 63;
  const int l15 = l & 15, g = l >> 4;
  const long r0 = ((long)blockIdx.x * 4 + w) * 16;

  __shared__ unsigned short TqS[4][16][72];
  __shared__ unsigned short TfS[4][16][136];

  bf16x8 ax[2];
#pragma unroll
  for (int kk = 0; kk < 2; kk++)
    ax[kk] = cvt8(x + (r0 + l15) * 64 + kk * 32 + g * 8);

  proj_chain(ax, Wq, bq, Wmq, bmq, q0w, fqw, TqS[w], TfS[w], r0, l15, g, l);
  proj_chain(ax, Wk, bk, Wmk, bmk, k0w, fkw, TqS[w], TfS[w], r0, l15, g, l);
}

// ---------------------------------------------------------------------------
// Kernel 2: fk column-sum partials (bh, part): rows part*256..+255.
// ---------------------------------------------------------------------------
__global__ __launch_bounds__(256) void k_colsum1(const unsigned short* __restrict__ fkw)
{
  const int bh = blockIdx.x, part = blockIdx.y;
  const int tid = threadIdx.x;
  const int cg = tid & 15, rg = tid >> 4;
  const unsigned short* fkp = fkw + ((long)bh * NN + part * 256 + rg * 16) * 128 + cg * 8;

  float a8[8] = {0.f, 0.f, 0.f, 0.f, 0.f, 0.f, 0.f, 0.f};
#pragma unroll
  for (int r = 0; r < 16; r++) {
    bf16x8 v = *(const bf16x8*)(fkp + (long)r * 128);
#pragma unroll
    for (int j = 0; j < 8; j++) a8[j] += bf2f((unsigned short)v[j]);
  }
  __shared__ float red[16][132];
#pragma unroll
  for (int j = 0; j < 8; j++) red[rg][cg * 8 + j] = a8[j];
  __syncthreads();
  if (tid < 128) {
    float s = 0.f;
#pragma unroll
    for (int r = 0; r < 16; r++) s += red[r][tid];
    g_part[(bh * 8 + part) * 128 + tid] = s;
  }
}

// ---------------------------------------------------------------------------
// Kernel 3a: pred normalizers (factorized dot with fk colsums).
// ---------------------------------------------------------------------------
__global__ __launch_bounds__(256) void k_normP(const unsigned short* __restrict__ fqw)
{
  const int bh = blockIdx.x, rg = blockIdx.y;   // (32, 16)
  const int tid = threadIdx.x;

  __shared__ float sfk[128];
  if (tid < 128) {
    float s = 0.f;
#pragma unroll
    for (int pt = 0; pt < 8; pt++) s += g_part[bh * 1024 + pt * 128 + tid];
    sfk[tid] = s;
  }
  __syncthreads();
  if (tid < 128) {
    const int row = rg * 128 + tid;
    const unsigned short* p = fqw + ((long)bh * NN + row) * 128;
    float d = 0.f;
#pragma unroll
    for (int i = 0; i < 16; i++) {
      bf16x8 v = *(const bf16x8*)(p + i * 8);
#pragma unroll
      for (int jj = 0; jj < 8; jj++) d += bf2f((unsigned short)v[jj]) * sfk[i * 8 + jj];
    }
    g_normP[bh * NN + row] = 1.0f / d;
  }
}

// ---------------------------------------------------------------------------
// Kernel 3b: true normalizers. Grid (32, 64): 32 rows/block, keys split
// across 4 waves. Runs before the write storm (clean L2).
// ---------------------------------------------------------------------------
__global__ __launch_bounds__(256) void k_normT(
    const unsigned short* __restrict__ q0w, const unsigned short* __restrict__ k0w)
{
  const int bh = blockIdx.x, rb = blockIdx.y * 32;
  const int tid = threadIdx.x;
  const int w = tid >> 6, l = tid & 63;
  const int l15 = l & 15, g = l >> 4;

  __shared__ float sred[2][4][16];
  const unsigned short* k0p = k0w + (long)bh * NN * 64;

#pragma unroll
  for (int tt = 0; tt < 2; tt++) {
    const unsigned short* qp = q0w + ((long)bh * NN + rb + tt * 16) * 64;
    bf16x8 a0 = *(const bf16x8*)(qp + l15 * 64 + g * 8);
    bf16x8 a1 = *(const bf16x8*)(qp + l15 * 64 + 32 + g * 8);
    float st[4] = {0.f, 0.f, 0.f, 0.f};
    for (int kt = w; kt < 128; kt += 4) {
      const unsigned short* bp = k0p + (long)(kt * 16 + l15) * 64 + g * 8;
      f32x4 acc = {0.f, 0.f, 0.f, 0.f};
      acc = mfma16(a0, *(const bf16x8*)bp, acc);
      acc = mfma16(a1, *(const bf16x8*)(bp + 32), acc);
#pragma unroll
      for (int j = 0; j < 4; j++) st[j] += __expf(acc[j] * 0.125f);
    }
#pragma unroll
    for (int j = 0; j < 4; j++) {
      float v = st[j];
      v += __shfl_xor(v, 1, 16);
      v += __shfl_xor(v, 2, 16);
      v += __shfl_xor(v, 4, 16);
      v += __shfl_xor(v, 8, 16);
      if (l15 == 0) sred[tt][w][g * 4 + j] = v;
    }
  }
  __syncthreads();
  if (tid < 32) {
    const int t2 = tid >> 4, rr = tid & 15;
    float s = sred[t2][0][rr] + sred[t2][1][rr] + sred[t2][2][rr] + sred[t2][3][rr];
    g_normT[bh * NN + rb + t2 * 16 + rr] = 1.0f / s;
  }
}

// ---------------------------------------------------------------------------
// Kernel 4: slab writer (v13 structure). Block = (bh, 128-key slab), 4 waves,
// 2 blocks/CU. fk/k0 slab LDS-resident; UNIFORM sweep of 128 row-groups.
// Store-data registers rotated 2-deep across rg parity.
// ---------------------------------------------------------------------------
__global__ __launch_bounds__(256, 2) void k_write(
    const unsigned short* __restrict__ q0w, const unsigned short* __restrict__ k0w,
    const unsigned short* __restrict__ fqw, const unsigned short* __restrict__ fkw,
    float* __restrict__ out)
{
  const int bh = blockIdx.x;          // 0..31
  const int slab = blockIdx.y;        // 0..15 (128-key slab)
  const int tid = threadIdx.x;
  const int w = tid >> 6, l = tid & 63;
  const int l15 = l & 15, g = l >> 4;

  __shared__ unsigned short fkS[128][136];  // slab operands (padded rows)
  __shared__ unsigned short k0S[128][72];
  __shared__ float obuf[2][16][132];        // [0]=pred strip, [1]=true strip

  const unsigned short* fkp = fkw + ((long)bh * NN + slab * 128) * 128;
  const unsigned short* k0p = k0w + ((long)bh * NN + slab * 128) * 64;
  const unsigned short* fqb = fqw + (long)bh * NN * 128;
  const unsigned short* q0b = q0w + (long)bh * NN * 64;
  const float* npb = g_normP + bh * NN;
  const float* ntb = g_normT + bh * NN;
  const long ob_p = (long)bh * NN * NN + slab * 128;
  const long ob_t = ob_p + (long)NBH * NN * NN;

  // ---- stage slab operands once ----
#pragma unroll
  for (int i = 0; i < 8; i++) {
    int c = i * 256 + tid, r = c >> 4, cc = c & 15;
    *(bf16x8*)&fkS[r][cc * 8] = *(const bf16x8*)(fkp + (long)r * 128 + cc * 8);
  }
#pragma unroll
  for (int i = 0; i < 4; i++) {
    int c = i * 256 + tid, r = c >> 3, cc = c & 7;
    *(bf16x8*)&k0S[r][cc * 8] = *(const bf16x8*)(k0p + (long)r * 64 + cc * 8);
  }
  __syncthreads();

  // ---- A-frag register sets (double: current / next) ----
  bf16x8 aq[4], bq_[4], ak[2], bk_[2];
  f32x4 aip, ait, bip, bit;
  // store-data registers, rotated 2-deep across rg parity
  f32x4 pA0, pA1, tA0, tA1, pB0, pB1, tB0, tB1;

#define PF(RG1, FQ, K0, IP, IT) {                                              \
    if ((RG1) < 128) {                                                         \
      const int qr_ = (RG1) * 16;                                              \
      _Pragma("unroll")                                                        \
      for (int kk = 0; kk < 4; kk++)                                           \
        FQ[kk] = *(const bf16x8*)(fqb + (long)(qr_ + l15) * 128 + kk * 32 + g * 8); \
      _Pragma("unroll")                                                        \
      for (int kk = 0; kk < 2; kk++)                                           \
        K0[kk] = *(const bf16x8*)(q0b + (long)(qr_ + l15) * 64 + kk * 32 + g * 8);  \
      IP = *(const f32x4*)(npb + qr_ + g * 4);                                 \
      IT = *(const f32x4*)(ntb + qr_ + g * 4);                                 \
    }                                                                          \
  }

#define CPRED(FQ, IP) {                                                        \
    _Pragma("unroll")                                                          \
    for (int t = 0; t < 2; t++) {                                              \
      const int key = w * 32 + t * 16 + l15;                                   \
      f32x4 acc = {0.f, 0.f, 0.f, 0.f};                                        \
      _Pragma("unroll")                                                        \
      for (int kk = 0; kk < 4; kk++)                                           \
        acc = mfma16(FQ[kk], *(const bf16x8*)&fkS[key][kk * 32 + g * 8], acc); \
      _Pragma("unroll")                                                        \
      for (int j = 0; j < 4; j++)                                              \
        obuf[0][g * 4 + j][key] = acc[j] * IP[j];                              \
    }                                                                          \
  }

#define CTRUE(K0, IT) {                                                        \
    _Pragma("unroll")                                                          \
    for (int t = 0; t < 2; t++) {                                              \
      const int key = w * 32 + t * 16 + l15;                                   \
      f32x4 acc = {0.f, 0.f, 0.f, 0.f};                                        \
      acc = mfma16(K0[0], *(const bf16x8*)&k0S[key][g * 8], acc);              \
      acc = mfma16(K0[1], *(const bf16x8*)&k0S[key][32 + g * 8], acc);         \
      _Pragma("unroll")                                                        \
      for (int j = 0; j < 4; j++)                                              \
        obuf[1][g * 4 + j][key] = __expf(acc[j] * 0.125f) * IT[j];             \
    }                                                                          \
  }

#define STOREV(PL, RG2, V0, V1) {                                              \
    const long ob = ((PL) ? ob_t : ob_p) + (long)((RG2) * 16) * NN;            \
    const int row0 = w * 4 + (l >> 5), col = (l & 31) * 4;                     \
    V0 = *(const f32x4*)&obuf[PL][row0][col];                                  \
    V1 = *(const f32x4*)&obuf[PL][row0 + 2][col];                              \
    *(f32x4*)(out + ob + (long)row0 * NN + col)       = V0;                    \
    *(f32x4*)(out + ob + (long)(row0 + 2) * NN + col) = V1;                    \
  }

#define BODY(RG, FQ, K0, IP, IT, NFQ, NK0, NIP, NIT, PV0, PV1, TV0, TV1) {     \
    /* --- pred segment --- */                                                 \
    PF((RG) + 1, NFQ, NK0, NIP, NIT);                                          \
    if ((RG) > 0) STOREV(1, (RG) - 1, TV0, TV1);                               \
    CPRED(FQ, IP);                                                             \
    asm volatile("s_waitcnt lgkmcnt(0)" ::: "memory");                         \
    __builtin_amdgcn_s_barrier();                                              \
    __builtin_amdgcn_sched_barrier(0);                                         \
    /* --- true segment --- */                                                 \
    STOREV(0, RG, PV0, PV1);                                                   \
    CTRUE(K0, IT);                                                             \
    asm volatile("s_waitcnt lgkmcnt(0)" ::: "memory");                         \
    __builtin_amdgcn_s_barrier();                                              \
    __builtin_amdgcn_sched_barrier(0);                                         \
  }

  PF(0, aq, ak, aip, ait);            // row-group 0 operands

#pragma unroll 1
  for (int rg2 = 0; rg2 < 64; rg2++) {
    BODY(2 * rg2,     aq, ak, aip, ait, bq_, bk_, bip, bit, pA0, pA1, tA0, tA1);
    BODY(2 * rg2 + 1, bq_, bk_, bip, bit, aq, ak, aip, ait, pB0, pB1, tB0, tB1);
  }
  STOREV(1, 127, tA0, tA1);           // drain: last true strip

#undef PF
#undef CPRED
#undef CTRUE
#undef STOREV
#undef BODY
}

extern "C" void kernel_launch(void* const* d_in, const int* in_sizes, int n_in,
                              void* d_out, int out_size, void* d_ws, size_t ws_size,
                              hipStream_t stream) {
  const float* x   = (const float*)d_in[0];
  const float* Wq  = (const float*)d_in[1];
  const float* bq  = (const float*)d_in[2];
  const float* Wk  = (const float*)d_in[3];
  const float* bk  = (const float*)d_in[4];
  const float* Wmq = (const float*)d_in[5];
  const float* bmq = (const float*)d_in[6];
  const float* Wmk = (const float*)d_in[7];
  const float* bmk = (const float*)d_in[8];
  float* out = (float*)d_out;

  // ws layout (bf16): q0[32][2048][64], k0[...], fq[32][2048][128], fk[...] = 48 MB
  unsigned short* q0w = (unsigned short*)d_ws;
  unsigned short* k0w = q0w + (long)NBH * NN * 64;
  unsigned short* fqw = k0w + (long)NBH * NN * 64;
  unsigned short* fkw = fqw + (long)NBH * NN * 128;

  hipLaunchKernelGGL(k_proj, dim3(1024), dim3(256), 0, stream,
                     x, Wq, bq, Wk, bk, Wmq, bmq, Wmk, bmk, q0w, k0w, fqw, fkw);
  hipLaunchKernelGGL(k_colsum1, dim3(NBH, 8), dim3(256), 0, stream, fkw);
  hipLaunchKernelGGL(k_normP, dim3(NBH, 16), dim3(256), 0, stream, fqw);
  hipLaunchKernelGGL(k_normT, dim3(NBH, 64), dim3(256), 0, stream, q0w, k0w);
  hipLaunchKernelGGL(k_write, dim3(NBH, 16), dim3(256), 0, stream,
                     q0w, k0w, fqw, fkw, out);
}